// Round 1
// baseline (1072.661 us; speedup 1.0000x reference)
//
#include <hip/hip_runtime.h>
#include <math.h>

// Problem constants (from reference)
#define NN 50000
#define EG 600000
#define EK 500000
#define H 128
#define INF 64

struct Theta9 { float t[9]; };  // t[i*3+k] = THETAS[i][k]

// ---------------------------------------------------------------- utilities
__device__ __forceinline__ float f4_at(const float4& v, int i) {
  return i == 0 ? v.x : i == 1 ? v.y : i == 2 ? v.z : v.w;
}
__device__ __forceinline__ void fma4(float4& a, float s, const float4& w) {
  a.x += s * w.x; a.y += s * w.y; a.z += s * w.z; a.w += s * w.w;
}
__device__ __forceinline__ float4 relu4(float4 a) {
  a.x = fmaxf(a.x, 0.f); a.y = fmaxf(a.y, 0.f);
  a.z = fmaxf(a.z, 0.f); a.w = fmaxf(a.w, 0.f);
  return a;
}

// ---------------------------------------------------------------- degree
__global__ __launch_bounds__(256) void k_deg(const int* __restrict__ dg,
    const int* __restrict__ dk, int* __restrict__ deg_g, int* __restrict__ deg_k) {
  int e = blockIdx.x * 256 + threadIdx.x;
  if (e < EG) atomicAdd(&deg_g[dg[e]], 1);
  if (e < EK) atomicAdd(&deg_k[dk[e]], 1);
}

// ---------------------------------------------------------------- scan (3-phase)
__global__ __launch_bounds__(256) void k_scan1(const int* __restrict__ in,
    int* __restrict__ rp, int* __restrict__ parts, int n) {
  __shared__ int s[256];
  int i = blockIdx.x * 256 + threadIdx.x;
  int t = threadIdx.x;
  int v = (i < n) ? in[i] : 0;
  s[t] = v;
  __syncthreads();
  for (int d = 1; d < 256; d <<= 1) {
    int u = 0;
    if (t >= d) u = s[t - d];
    __syncthreads();
    s[t] += u;
    __syncthreads();
  }
  if (i < n) rp[i + 1] = s[t];
  if (t == 255) parts[blockIdx.x] = s[255];
}

__global__ __launch_bounds__(256) void k_scan2(int* __restrict__ parts, int nb) {
  __shared__ int s[256];
  int t = threadIdx.x;
  int orig = (t < nb) ? parts[t] : 0;
  s[t] = orig;
  __syncthreads();
  for (int d = 1; d < 256; d <<= 1) {
    int u = 0;
    if (t >= d) u = s[t - d];
    __syncthreads();
    s[t] += u;
    __syncthreads();
  }
  if (t < nb) parts[t] = s[t] - orig;  // exclusive offsets
}

__global__ __launch_bounds__(256) void k_scan3(int* __restrict__ rp,
    const int* __restrict__ parts, int n) {
  int i = blockIdx.x * 256 + threadIdx.x;
  if (i < n) rp[i + 1] += parts[blockIdx.x];
  if (i == 0) rp[0] = 0;
}

// ---------------------------------------------------------------- dinv
__global__ __launch_bounds__(256) void k_dinv(const int* __restrict__ dg,
    const int* __restrict__ dk, float* __restrict__ og, float* __restrict__ ok_) {
  int i = blockIdx.x * 256 + threadIdx.x;
  if (i < NN) {
    int a = dg[i]; if (a < 1) a = 1;
    int b = dk[i]; if (b < 1) b = 1;
    og[i]  = 1.f / sqrtf((float)a);
    ok_[i] = 1.f / sqrtf((float)b);
  }
}

// ---------------------------------------------------------------- CSR fill
__global__ __launch_bounds__(256) void k_fill(const int* __restrict__ sg,
    const int* __restrict__ dg, const int* __restrict__ sk, const int* __restrict__ dk,
    const int* __restrict__ rpg, const int* __restrict__ rpk,
    int* __restrict__ curg, int* __restrict__ curk,
    int* __restrict__ adjg, int* __restrict__ adjk) {
  int e = blockIdx.x * 256 + threadIdx.x;
  if (e < EG) {
    int d = dg[e];
    int p = atomicAdd(&curg[d], 1);
    adjg[rpg[d] + p] = sg[e];
  }
  if (e < EK) {
    int d = dk[e];
    int p = atomicAdd(&curk[d], 1);
    adjk[rpk[d] + p] = sk[e];
  }
}

// ---------------------------------------------------------------- transpose (weights)
__global__ __launch_bounds__(256) void k_transpose(const float* __restrict__ A,
    float* __restrict__ At, int R, int C) {
  int i = blockIdx.x * 256 + threadIdx.x;
  if (i < R * C) {
    int r = i / C, c = i % C;
    At[c * R + r] = A[i];
  }
}

// ---------------------------------------------------------------- combined conv matrices
// A[k][j] = sum_i ( c_i[k] * sum_m Wc_i[m][k]*W3[j][i*128+m]  +  alpha_i * W3[j][i*128+k] )
// B[k][j] = sum_i beta_i[k]  * W3[j][i*128+k]
// C[k][j] = sum_i gamma_i[k] * W3[j][i*128+k]
// with c_i = th0*diag_i0, alpha_i = th1+th2,
//      beta_i = -((th1+th2)*diag_i1 + th2*diag_i2), gamma_i = th2*diag_i1*diag_i2
__global__ __launch_bounds__(256) void k_genmat(const float* __restrict__ diag,
    const float* __restrict__ Wc, const float* __restrict__ W3, Theta9 th,
    float* __restrict__ A, float* __restrict__ B, float* __restrict__ C) {
  int id = blockIdx.x * 256 + threadIdx.x;  // id = k*128 + j
  int k = id >> 7, j = id & 127;
  float a = 0.f, b = 0.f, c = 0.f;
  for (int i = 0; i < 3; i++) {
    float t0 = th.t[i * 3 + 0], t1 = th.t[i * 3 + 1], t2 = th.t[i * 3 + 2];
    float d0 = diag[(i * 3 + 0) * H + k];
    float d1 = diag[(i * 3 + 1) * H + k];
    float d2 = diag[(i * 3 + 2) * H + k];
    float ci = t0 * d0;
    float alpha = t1 + t2;
    float beta  = -((t1 + t2) * d1 + t2 * d2);
    float gamma = t2 * d1 * d2;
    float w3kj = W3[j * 384 + i * H + k];
    if (ci != 0.f) {
      const float* Wi = Wc + i * H * H;
      float g = 0.f;
      for (int m = 0; m < H; m++)
        g += Wi[m * H + k] * W3[j * 384 + i * H + m];
      a += ci * g;
    }
    a += alpha * w3kj;
    b += beta * w3kj;
    c += gamma * w3kj;
  }
  A[id] = a; B[id] = b; C[id] = c;
}

// bias[j] = b3[j] + sum_i sum_m bc[i][m] * W3[j][i*128+m]
__global__ __launch_bounds__(256) void k_genbias(const float* __restrict__ bc,
    const float* __restrict__ W3, const float* __restrict__ b3, float* __restrict__ bias) {
  int j = threadIdx.x;
  float s = b3[j];
  for (int i = 0; i < 3; i++)
    for (int m = 0; m < H; m++)
      s += bc[i * H + m] * W3[j * 384 + i * H + m];
  bias[j] = s;
}

// ---------------------------------------------------------------- GEMM helper
// 32 threads per 4-node group; each thread owns 4 outputs (lane*4..lane*4+3).
template<int K>
__device__ __forceinline__ void gemm_block(const float* __restrict__ x0,
    const float* __restrict__ Wt, int lane,
    float4& a0, float4& a1, float4& a2, float4& a3) {
  for (int k = 0; k < K; k += 4) {
    float4 xa = *(const float4*)(x0 + k);
    float4 xb = *(const float4*)(x0 + K + k);
    float4 xc = *(const float4*)(x0 + 2 * K + k);
    float4 xd = *(const float4*)(x0 + 3 * K + k);
#pragma unroll
    for (int kk = 0; kk < 4; kk++) {
      float4 w = *(const float4*)(Wt + (k + kk) * H + lane * 4);
      fma4(a0, f4_at(xa, kk), w);
      fma4(a1, f4_at(xb, kk), w);
      fma4(a2, f4_at(xc, kk), w);
      fma4(a3, f4_at(xd, kk), w);
    }
  }
}

template<int K, bool RELU>
__global__ __launch_bounds__(256) void k_lin(const float* __restrict__ X,
    const float* __restrict__ Wt, const float* __restrict__ bias,
    float* __restrict__ Y) {
  int g = blockIdx.x * blockDim.x + threadIdx.x;
  int grp = g >> 5, lane = g & 31;
  int n0 = grp * 4;
  if (n0 >= NN) return;
  float4 b4 = *(const float4*)(bias + lane * 4);
  float4 a0 = b4, a1 = b4, a2 = b4, a3 = b4;
  gemm_block<K>(X + (size_t)n0 * K, Wt, lane, a0, a1, a2, a3);
  if (RELU) { a0 = relu4(a0); a1 = relu4(a1); a2 = relu4(a2); a3 = relu4(a3); }
  float* y = Y + (size_t)n0 * H + lane * 4;
  *(float4*)(y) = a0;
  *(float4*)(y + H) = a1;
  *(float4*)(y + 2 * H) = a2;
  *(float4*)(y + 3 * H) = a3;
}

// 3-input fused GEMM: Y = relu(X0*A + X1*B + X2*C + bias)
__global__ __launch_bounds__(256) void k_lin3(const float* __restrict__ X0,
    const float* __restrict__ X1, const float* __restrict__ X2,
    const float* __restrict__ A, const float* __restrict__ B,
    const float* __restrict__ C, const float* __restrict__ bias,
    float* __restrict__ Y) {
  int g = blockIdx.x * blockDim.x + threadIdx.x;
  int grp = g >> 5, lane = g & 31;
  int n0 = grp * 4;
  if (n0 >= NN) return;
  float4 b4 = *(const float4*)(bias + lane * 4);
  float4 a0 = b4, a1 = b4, a2 = b4, a3 = b4;
  gemm_block<H>(X0 + (size_t)n0 * H, A, lane, a0, a1, a2, a3);
  gemm_block<H>(X1 + (size_t)n0 * H, B, lane, a0, a1, a2, a3);
  gemm_block<H>(X2 + (size_t)n0 * H, C, lane, a0, a1, a2, a3);
  a0 = relu4(a0); a1 = relu4(a1); a2 = relu4(a2); a3 = relu4(a3);
  float* y = Y + (size_t)n0 * H + lane * 4;
  *(float4*)(y) = a0;
  *(float4*)(y + H) = a1;
  *(float4*)(y + 2 * H) = a2;
  *(float4*)(y + 3 * H) = a3;
}

// ---------------------------------------------------------------- SpMM: Y[n] = dinv[n]*sum_{s in adj(n)} X[s]*dinv[s]
__global__ __launch_bounds__(256) void k_spmm(const float* __restrict__ X,
    const float* __restrict__ dinv, const int* __restrict__ rp,
    const int* __restrict__ adj, float* __restrict__ Y) {
  int g = blockIdx.x * blockDim.x + threadIdx.x;
  int n = g >> 5, lane = g & 31;
  if (n >= NN) return;
  float4 acc = make_float4(0.f, 0.f, 0.f, 0.f);
  int beg = rp[n], end = rp[n + 1];
  for (int e = beg; e < end; e++) {
    int s = adj[e];
    float ds = dinv[s];
    float4 xv = *(const float4*)(X + (size_t)s * H + lane * 4);
    fma4(acc, ds, xv);
  }
  float dn = dinv[n];
  acc.x *= dn; acc.y *= dn; acc.z *= dn; acc.w *= dn;
  *(float4*)(Y + (size_t)n * H + lane * 4) = acc;
}

// ---------------------------------------------------------------- attention score sums
__global__ __launch_bounds__(256) void k_attn(const float* __restrict__ Ho,
    const float* __restrict__ Hk, const float* __restrict__ Wa1t,
    const float* __restrict__ ba1, const float* __restrict__ Wa2,
    float* __restrict__ sums) {
  int g = blockIdx.x * blockDim.x + threadIdx.x;
  int n = g >> 5, lane = g & 31;
  float po = 0.f, pk = 0.f;
  if (n < NN) {
    float4 bb = *(const float4*)(ba1 + lane * 4);
    float4 w2 = *(const float4*)(Wa2 + lane * 4);
    const float* ho = Ho + (size_t)n * H;
    const float* hk = Hk + (size_t)n * H;
    float4 ao = bb, ak = bb;
    for (int k = 0; k < H; k++) {
      float4 w = *(const float4*)(Wa1t + k * H + lane * 4);
      fma4(ao, ho[k], w);
      fma4(ak, hk[k], w);
    }
    po = w2.x * tanhf(ao.x) + w2.y * tanhf(ao.y) + w2.z * tanhf(ao.z) + w2.w * tanhf(ao.w);
    pk = w2.x * tanhf(ak.x) + w2.y * tanhf(ak.y) + w2.z * tanhf(ak.z) + w2.w * tanhf(ak.w);
  }
  for (int d = 16; d > 0; d >>= 1) {
    po += __shfl_down(po, d, 32);
    pk += __shfl_down(pk, d, 32);
  }
  __shared__ float ro[8], rk[8];
  if (lane == 0) { ro[threadIdx.x >> 5] = po; rk[threadIdx.x >> 5] = pk; }
  __syncthreads();
  if (threadIdx.x == 0) {
    float so = 0.f, sk = 0.f;
    for (int i = 0; i < 8; i++) { so += ro[i]; sk += rk[i]; }
    atomicAdd(&sums[0], so);
    atomicAdd(&sums[1], sk);
  }
}

// ---------------------------------------------------------------- final: beta-blend + classifier
__global__ __launch_bounds__(256) void k_final(const float* __restrict__ Ho,
    const float* __restrict__ Hk, const float* __restrict__ sums,
    const float* __restrict__ W4, const float* __restrict__ b4,
    float* __restrict__ out) {
  int g = blockIdx.x * blockDim.x + threadIdx.x;
  int n = g >> 5, lane = g & 31;
  if (n >= NN) return;
  float mo = sums[0] * (1.f / NN);
  float mk = sums[1] * (1.f / NN);
  float mx = fmaxf(mo, mk);
  float eo = expf(mo - mx), ek = expf(mk - mx);
  float inv = 1.f / (eo + ek);
  float bo = eo * inv, bk2 = ek * inv;
  float4 ho = *(const float4*)(Ho + (size_t)n * H + lane * 4);
  float4 hk = *(const float4*)(Hk + (size_t)n * H + lane * 4);
  float4 emb;
  emb.x = bo * ho.x + bk2 * hk.x;
  emb.y = bo * ho.y + bk2 * hk.y;
  emb.z = bo * ho.z + bk2 * hk.z;
  emb.w = bo * ho.w + bk2 * hk.w;
  *(float4*)(out + 2 * NN + (size_t)n * H + lane * 4) = emb;
  float4 w0 = *(const float4*)(W4 + lane * 4);
  float4 w1 = *(const float4*)(W4 + H + lane * 4);
  float p0 = emb.x * w0.x + emb.y * w0.y + emb.z * w0.z + emb.w * w0.w;
  float p1 = emb.x * w1.x + emb.y * w1.y + emb.z * w1.z + emb.w * w1.w;
  for (int d = 16; d > 0; d >>= 1) {
    p0 += __shfl_down(p0, d, 32);
    p1 += __shfl_down(p1, d, 32);
  }
  if (lane == 0) {
    out[n * 2 + 0] = p0 + b4[0];
    out[n * 2 + 1] = p1 + b4[1];
  }
}

// ================================================================ host
extern "C" void kernel_launch(void* const* d_in, const int* in_sizes, int n_in,
                              void* d_out, int out_size, void* d_ws, size_t ws_size,
                              hipStream_t stream) {
  const float* x      = (const float*)d_in[0];
  const int*   src_g  = (const int*)d_in[1];
  const int*   dst_g  = (const int*)d_in[2];
  const int*   src_k  = (const int*)d_in[3];
  const int*   dst_k  = (const int*)d_in[4];
  const float* W1     = (const float*)d_in[5];
  const float* b1     = (const float*)d_in[6];
  const float* W2     = (const float*)d_in[7];
  const float* b2     = (const float*)d_in[8];
  const float* diag_g = (const float*)d_in[9];
  const float* Wc_g   = (const float*)d_in[10];
  const float* bc_g   = (const float*)d_in[11];
  const float* diag_k = (const float*)d_in[12];
  const float* Wc_k   = (const float*)d_in[13];
  const float* bc_k   = (const float*)d_in[14];
  const float* W3     = (const float*)d_in[15];
  const float* b3     = (const float*)d_in[16];
  const float* Wk     = (const float*)d_in[17];
  const float* bk     = (const float*)d_in[18];
  const float* Wa1    = (const float*)d_in[19];
  const float* ba1    = (const float*)d_in[20];
  const float* Wa2    = (const float*)d_in[21];
  const float* W4     = (const float*)d_in[22];
  const float* b4     = (const float*)d_in[23];
  float* out = (float*)d_out;

  // ---- workspace bump allocator (256B aligned)
  char* base = (char*)d_ws;
  size_t off = 0;
  auto alloc = [&](size_t bytes) -> char* {
    char* r = base + off;
    off = (off + bytes + 255) & ~(size_t)255;
    return r;
  };
  // zero region (memset each launch): deg_g, deg_k, cur_g, cur_k, sums
  int* deg_g = (int*)alloc(NN * 4);
  int* deg_k = (int*)alloc(NN * 4);
  int* cur_g = (int*)alloc(NN * 4);
  int* cur_k = (int*)alloc(NN * 4);
  float* sums = (float*)alloc(256);
  size_t zero_bytes = off;

  int* rp_g    = (int*)alloc((NN + 1) * 4);
  int* rp_k    = (int*)alloc((NN + 1) * 4);
  int* parts_g = (int*)alloc(256 * 4);
  int* parts_k = (int*)alloc(256 * 4);
  int* adj_g   = (int*)alloc(EG * 4);
  int* adj_k   = (int*)alloc(EK * 4);
  float* dinv_g = (float*)alloc(NN * 4);
  float* dinv_k = (float*)alloc(NN * 4);
  float* Wt1  = (float*)alloc(INF * H * 4);
  float* Wt2  = (float*)alloc(H * H * 4);
  float* Wa1t = (float*)alloc(H * H * 4);
  float* Ag = (float*)alloc(H * H * 4);
  float* Bg = (float*)alloc(H * H * 4);
  float* Cg = (float*)alloc(H * H * 4);
  float* biasg = (float*)alloc(H * 4);
  float* Ak = (float*)alloc(H * H * 4);
  float* Bk = (float*)alloc(H * H * 4);
  float* Ck = (float*)alloc(H * H * 4);
  float* biask = (float*)alloc(H * 4);
  float* B0 = (float*)alloc((size_t)NN * H * 4);  // t1, later h_o
  float* B1 = (float*)alloc((size_t)NN * H * 4);  // h
  float* B2 = (float*)alloc((size_t)NN * H * 4);  // u
  float* B3 = (float*)alloc((size_t)NN * H * 4);  // w
  float* B4 = (float*)alloc((size_t)NN * H * 4);  // h_knn
  (void)ws_size; (void)in_sizes; (void)n_in; (void)out_size;

  hipMemsetAsync(d_ws, 0, zero_bytes, stream);

  const int EB = (EG + 255) / 256;        // 2344 (covers EK too)
  const int SB = (NN + 255) / 256;        // 196
  const int GB = NN * 32 / 256;           // 6250 (1 node / 32 threads)
  const int LB = (NN / 4 * 32 + 255) / 256;  // 1563 (4 nodes / 32 threads)

  // CSR build + dinv
  k_deg<<<EB, 256, 0, stream>>>(dst_g, dst_k, deg_g, deg_k);
  k_scan1<<<SB, 256, 0, stream>>>(deg_g, rp_g, parts_g, NN);
  k_scan1<<<SB, 256, 0, stream>>>(deg_k, rp_k, parts_k, NN);
  k_scan2<<<1, 256, 0, stream>>>(parts_g, SB);
  k_scan2<<<1, 256, 0, stream>>>(parts_k, SB);
  k_scan3<<<SB, 256, 0, stream>>>(rp_g, parts_g, NN);
  k_scan3<<<SB, 256, 0, stream>>>(rp_k, parts_k, NN);
  k_dinv<<<SB, 256, 0, stream>>>(deg_g, deg_k, dinv_g, dinv_k);
  k_fill<<<EB, 256, 0, stream>>>(src_g, dst_g, src_k, dst_k, rp_g, rp_k,
                                 cur_g, cur_k, adj_g, adj_k);

  // weight prep
  k_transpose<<<(H * INF + 255) / 256, 256, 0, stream>>>(W1, Wt1, H, INF);
  k_transpose<<<(H * H + 255) / 256, 256, 0, stream>>>(W2, Wt2, H, H);
  k_transpose<<<(H * H + 255) / 256, 256, 0, stream>>>(Wa1, Wa1t, H, H);
  Theta9 thG = {{3.f, -3.f, 0.75f, 0.f, 3.f, -1.5f, 0.f, 0.f, 0.75f}};
  Theta9 thK = {{1.f, 1.f, 1.f, 1.f, 1.f, 1.f, 1.f, 1.f, 1.f}};
  k_genmat<<<64, 256, 0, stream>>>(diag_g, Wc_g, W3, thG, Ag, Bg, Cg);
  k_genmat<<<64, 256, 0, stream>>>(diag_k, Wc_k, Wk, thK, Ak, Bk, Ck);
  k_genbias<<<1, 128, 0, stream>>>(bc_g, W3, b3, biasg);
  k_genbias<<<1, 128, 0, stream>>>(bc_k, Wk, bk, biask);

  // input MLP
  k_lin<INF, true><<<LB, 256, 0, stream>>>(x, Wt1, b1, B0);   // t1
  k_lin<H, true><<<LB, 256, 0, stream>>>(B0, Wt2, b2, B1);    // h

  // graph G: u, w, fused conv+fusion
  k_spmm<<<GB, 256, 0, stream>>>(B1, dinv_g, rp_g, adj_g, B2);  // u_g
  k_spmm<<<GB, 256, 0, stream>>>(B2, dinv_g, rp_g, adj_g, B3);  // w_g
  k_lin3<<<LB, 256, 0, stream>>>(B1, B2, B3, Ag, Bg, Cg, biasg, B0);  // h_o

  // graph K
  k_spmm<<<GB, 256, 0, stream>>>(B1, dinv_k, rp_k, adj_k, B2);  // u_k
  k_spmm<<<GB, 256, 0, stream>>>(B2, dinv_k, rp_k, adj_k, B3);  // w_k
  k_lin3<<<LB, 256, 0, stream>>>(B1, B2, B3, Ak, Bk, Ck, biask, B4);  // h_knn

  // attention + output
  k_attn<<<GB, 256, 0, stream>>>(B0, B4, Wa1t, ba1, Wa2, sums);
  k_final<<<GB, 256, 0, stream>>>(B0, B4, sums, W4, b4, out);
}